// Round 1
// baseline (679.108 us; speedup 1.0000x reference)
//
#include <hip/hip_runtime.h>
#include <math.h>

// Problem constants (from reference)
constexpr int kN2 = 180224, kN1 = 11264, kN0 = 1024;
constexpr int kE1 = 168960, kE2 = 10240;
constexpr int kIN = 602, kHID = 256, kOUT = 41;

// ---------------------------------------------------------------------------
// Kernel 1: scatter x[src1] rows into agg1[dst1], count edges per dst.
// Block per edge, 128 threads sweep the 602-float row (coalesced 2.4KB read).
// ---------------------------------------------------------------------------
__global__ __launch_bounds__(128)
void scatter1_kernel(const float* __restrict__ x, const int* __restrict__ src,
                     const int* __restrict__ dst, float* __restrict__ agg,
                     float* __restrict__ cnt) {
    const int e = blockIdx.x;
    const int s = src[e];
    const int d = dst[e];
    const float* xr = x + (size_t)s * kIN;
    float* ar = agg + (size_t)d * kIN;
    for (int f = threadIdx.x; f < kIN; f += 128)
        atomicAdd(&ar[f], xr[f]);
    if (threadIdx.x == 0) atomicAdd(&cnt[d], 1.0f);
}

// ---------------------------------------------------------------------------
// Kernel 2: h = relu( (agg1/cnt) @ W1l + b1 + x[:N1] @ W1r )
// Fused as one K-loop over both operand pairs. Block: 256 threads = one per
// hidden column j; TM=8 nodes register-blocked so each W load is reused 8x.
// A-operands staged in LDS per 64-wide K chunk (broadcast reads, no
// conflicts).
// ---------------------------------------------------------------------------
constexpr int TM = 8;
constexpr int KB = 64;

__global__ __launch_bounds__(256)
void layer1_kernel(const float* __restrict__ agg, const float* __restrict__ cnt,
                   const float* __restrict__ x, const float* __restrict__ W1l,
                   const float* __restrict__ W1r, const float* __restrict__ b1,
                   float* __restrict__ h) {
    __shared__ float sa[TM][KB];
    __shared__ float sx[TM][KB];
    __shared__ float sinv[TM];
    const int n0 = blockIdx.x * TM;
    const int j = threadIdx.x;

    if (j < TM) sinv[j] = 1.0f / fmaxf(cnt[n0 + j], 1.0f);

    float acc[TM];
    const float bj = b1[j];
#pragma unroll
    for (int m = 0; m < TM; ++m) acc[m] = bj;
    __syncthreads();  // sinv visible

    for (int k0 = 0; k0 < kIN; k0 += KB) {
        const int kb = min(KB, kIN - k0);
        // stage TM rows x kb cols of both A operands
        for (int t = j; t < TM * kb; t += 256) {
            const int m = t / kb;
            const int k = t - m * kb;
            const size_t gi = (size_t)(n0 + m) * kIN + k0 + k;
            sa[m][k] = agg[gi] * sinv[m];
            sx[m][k] = x[gi];
        }
        __syncthreads();
        for (int k = 0; k < kb; ++k) {
            const float wl = W1l[(size_t)(k0 + k) * kHID + j];
            const float wr = W1r[(size_t)(k0 + k) * kHID + j];
#pragma unroll
            for (int m = 0; m < TM; ++m)
                acc[m] += sa[m][k] * wl + sx[m][k] * wr;
        }
        __syncthreads();
    }
#pragma unroll
    for (int m = 0; m < TM; ++m)
        h[(size_t)(n0 + m) * kHID + j] = fmaxf(acc[m], 0.0f);
}

// ---------------------------------------------------------------------------
// Kernel 3: scatter h[src2] rows into agg2[dst2] (256 floats/row).
// ---------------------------------------------------------------------------
__global__ __launch_bounds__(256)
void scatter2_kernel(const float* __restrict__ h, const int* __restrict__ src,
                     const int* __restrict__ dst, float* __restrict__ agg,
                     float* __restrict__ cnt) {
    const int e = blockIdx.x;
    const int s = src[e];
    const int d = dst[e];
    atomicAdd(&agg[(size_t)d * kHID + threadIdx.x],
              h[(size_t)s * kHID + threadIdx.x]);
    if (threadIdx.x == 0) atomicAdd(&cnt[d], 1.0f);
}

// ---------------------------------------------------------------------------
// Kernel 4: logits = (agg2/cnt) @ W2l + b2 + h[:N0] @ W2r ; log_softmax row.
// One wave (64 threads) per output node; 41 active columns; full-wave
// shuffle reductions for max and sum-exp.
// ---------------------------------------------------------------------------
__global__ __launch_bounds__(64)
void layer2_kernel(const float* __restrict__ agg2, const float* __restrict__ cnt2,
                   const float* __restrict__ h, const float* __restrict__ W2l,
                   const float* __restrict__ W2r, const float* __restrict__ b2,
                   float* __restrict__ out) {
    __shared__ float sa[kHID];
    __shared__ float sh[kHID];
    const int n = blockIdx.x;
    const int t = threadIdx.x;
    const float inv = 1.0f / fmaxf(cnt2[n], 1.0f);
    for (int k = t; k < kHID; k += 64) {
        sa[k] = agg2[(size_t)n * kHID + k] * inv;
        sh[k] = h[(size_t)n * kHID + k];
    }
    __syncthreads();

    float logit = 0.0f;
    if (t < kOUT) {
        logit = b2[t];
        for (int k = 0; k < kHID; ++k)
            logit += sa[k] * W2l[k * kOUT + t] + sh[k] * W2r[k * kOUT + t];
    }
    // wave max over 41 valid lanes
    float m = (t < kOUT) ? logit : -INFINITY;
#pragma unroll
    for (int off = 32; off >= 1; off >>= 1)
        m = fmaxf(m, __shfl_xor(m, off));
    float e = (t < kOUT) ? expf(logit - m) : 0.0f;
    float s = e;
#pragma unroll
    for (int off = 32; off >= 1; off >>= 1)
        s += __shfl_xor(s, off);
    if (t < kOUT)
        out[(size_t)n * kOUT + t] = logit - m - logf(s);
}

// ---------------------------------------------------------------------------
extern "C" void kernel_launch(void* const* d_in, const int* in_sizes, int n_in,
                              void* d_out, int out_size, void* d_ws, size_t ws_size,
                              hipStream_t stream) {
    const float* x   = (const float*)d_in[0];
    const int*   src1 = (const int*)d_in[1];
    const int*   dst1 = (const int*)d_in[2];
    const int*   src2 = (const int*)d_in[3];
    const int*   dst2 = (const int*)d_in[4];
    const float* W1l = (const float*)d_in[5];
    const float* W1r = (const float*)d_in[6];
    const float* b1  = (const float*)d_in[7];
    const float* W2l = (const float*)d_in[8];
    const float* W2r = (const float*)d_in[9];
    const float* b2  = (const float*)d_in[10];
    float* out = (float*)d_out;

    float* ws = (float*)d_ws;
    float* agg1 = ws;                                  // kN1*kIN
    float* cnt1 = agg1 + (size_t)kN1 * kIN;            // kN1
    float* agg2 = cnt1 + kN1;                          // kN0*kHID
    float* cnt2 = agg2 + (size_t)kN0 * kHID;           // kN0
    float* h    = cnt2 + kN0;                          // kN1*kHID

    const size_t zero_bytes =
        ((size_t)kN1 * kIN + kN1 + (size_t)kN0 * kHID + kN0) * sizeof(float);
    hipMemsetAsync(d_ws, 0, zero_bytes, stream);

    scatter1_kernel<<<kE1, 128, 0, stream>>>(x, src1, dst1, agg1, cnt1);
    layer1_kernel<<<kN1 / TM, 256, 0, stream>>>(agg1, cnt1, x, W1l, W1r, b1, h);
    scatter2_kernel<<<kE2, kHID, 0, stream>>>(h, src2, dst2, agg2, cnt2);
    layer2_kernel<<<kN0, 64, 0, stream>>>(agg2, cnt2, h, W2l, W2r, b2, out);
}

// Round 2
// 408.961 us; speedup vs baseline: 1.6606x; 1.6606x over previous
//
#include <hip/hip_runtime.h>
#include <math.h>

// Problem constants (from reference)
constexpr int kN2 = 180224, kN1 = 11264, kN0 = 1024;
constexpr int kE1 = 168960, kE2 = 10240;
constexpr int kIN = 602, kHID = 256, kOUT = 41;

// ---------------------------------------------------------------------------
// CSR build for layer-1 edges: histogram -> exclusive scan -> bucket scatter.
// Replaces 102M float atomics with ~340K int atomics.
// ---------------------------------------------------------------------------
__global__ __launch_bounds__(256)
void hist1_kernel(const int* __restrict__ dst, int* __restrict__ cnt) {
    const int e = blockIdx.x * 256 + threadIdx.x;
    if (e < kE1) atomicAdd(&cnt[dst[e]], 1);
}

// Single-block exclusive scan over kN1 = 11264 = 256 * 44 counts.
__global__ __launch_bounds__(256)
void scan1_kernel(const int* __restrict__ cnt, int* __restrict__ off) {
    __shared__ int part[256];
    const int t = threadIdx.x;
    constexpr int CH = kN1 / 256;  // 44
    const int base = t * CH;
    int s = 0;
    for (int i = 0; i < CH; ++i) s += cnt[base + i];
    part[t] = s;
    __syncthreads();
    // Hillis-Steele inclusive scan of the 256 partials
    for (int ofs = 1; ofs < 256; ofs <<= 1) {
        int v = (t >= ofs) ? part[t - ofs] : 0;
        __syncthreads();
        if (t >= ofs) part[t] += v;
        __syncthreads();
    }
    int run = (t == 0) ? 0 : part[t - 1];
    for (int i = 0; i < CH; ++i) {
        off[base + i] = run;
        run += cnt[base + i];
    }
    if (t == 255) off[kN1] = run;  // == kE1
}

__global__ __launch_bounds__(256)
void bucket1_kernel(const int* __restrict__ src, const int* __restrict__ dst,
                    const int* __restrict__ off, int* __restrict__ cur,
                    int* __restrict__ ebuf) {
    const int e = blockIdx.x * 256 + threadIdx.x;
    if (e < kE1) {
        const int d = dst[e];
        const int p = atomicAdd(&cur[d], 1);
        ebuf[off[d] + p] = src[e];
    }
}

// ---------------------------------------------------------------------------
// Aggregation layer 1: block per dst node, no atomics. 128 threads sweep the
// 602-float rows of the node's sources (coalesced), accumulate in registers,
// write the mean once (pre-divided, so the GEMM needs no counts).
// ---------------------------------------------------------------------------
__global__ __launch_bounds__(128)
void aggregate1_kernel(const float* __restrict__ x, const int* __restrict__ off,
                       const int* __restrict__ ebuf, float* __restrict__ agg) {
    const int d = blockIdx.x;
    const int t = threadIdx.x;
    const int b = off[d], e = off[d + 1];
    float acc[5] = {0.f, 0.f, 0.f, 0.f, 0.f};
    for (int i = b; i < e; ++i) {
        const float* row = x + (size_t)ebuf[i] * kIN;
#pragma unroll
        for (int r = 0; r < 4; ++r) acc[r] += row[t + r * 128];
        if (t < kIN - 512) acc[4] += row[t + 512];
    }
    const float inv = 1.0f / fmaxf((float)(e - b), 1.0f);
    float* ar = agg + (size_t)d * kIN;
#pragma unroll
    for (int r = 0; r < 4; ++r) ar[t + r * 128] = acc[r] * inv;
    if (t < kIN - 512) ar[t + 512] = acc[4] * inv;
}

// ---------------------------------------------------------------------------
// Layer-1 GEMM: h = relu(agg @ W1l + b1 + x[:N1] @ W1r)
// 128x64 block tile, 256 threads, 8x4 register tile, K-chunk 32.
// A panels stored transposed in LDS (pad +4 keeps float4 reads 16B-aligned
// and broadcast-conflict-free; 4-way write conflicts only on staging, which
// is 6x rarer than fragment reads).
// ---------------------------------------------------------------------------
constexpr int BM = 128, BN = 64, KB = 32;

__global__ __launch_bounds__(256)
void layer1_kernel(const float* __restrict__ agg, const float* __restrict__ x,
                   const float* __restrict__ W1l, const float* __restrict__ W1r,
                   const float* __restrict__ b1, float* __restrict__ h) {
    __shared__ float saT[KB][BM + 4];
    __shared__ float sxT[KB][BM + 4];
    __shared__ float swl[KB][BN];
    __shared__ float swr[KB][BN];
    const int n0 = blockIdx.x * BM;
    const int j0 = blockIdx.y * BN;
    const int t = threadIdx.x;
    const int tx = t & 15;   // column group: 4 cols
    const int ty = t >> 4;   // row group: 8 rows

    float acc[8][4];
#pragma unroll
    for (int r = 0; r < 8; ++r)
#pragma unroll
        for (int c = 0; c < 4; ++c) acc[r][c] = 0.f;

    for (int k0 = 0; k0 < kIN; k0 += KB) {
        // stage A panels (transposed, zero-fill K tail)
        for (int i = t; i < BM * KB; i += 256) {
            const int r = i >> 5, k = i & 31;
            const int gk = k0 + k;
            float va = 0.f, vx = 0.f;
            if (gk < kIN) {
                const size_t gi = (size_t)(n0 + r) * kIN + gk;
                va = agg[gi];
                vx = x[gi];
            }
            saT[k][r] = va;
            sxT[k][r] = vx;
        }
        // stage W panels
        for (int i = t; i < KB * BN; i += 256) {
            const int k = i >> 6, j = i & 63;
            const int gk = k0 + k;
            float vl = 0.f, vr = 0.f;
            if (gk < kIN) {
                vl = W1l[(size_t)gk * kHID + j0 + j];
                vr = W1r[(size_t)gk * kHID + j0 + j];
            }
            swl[k][j] = vl;
            swr[k][j] = vr;
        }
        __syncthreads();
#pragma unroll 4
        for (int k = 0; k < KB; ++k) {
            const float4 a0 = *(const float4*)&saT[k][ty * 8];
            const float4 a1 = *(const float4*)&saT[k][ty * 8 + 4];
            const float4 x0 = *(const float4*)&sxT[k][ty * 8];
            const float4 x1 = *(const float4*)&sxT[k][ty * 8 + 4];
            const float4 wl = *(const float4*)&swl[k][tx * 4];
            const float4 wr = *(const float4*)&swr[k][tx * 4];
            const float ar[8] = {a0.x, a0.y, a0.z, a0.w, a1.x, a1.y, a1.z, a1.w};
            const float xr[8] = {x0.x, x0.y, x0.z, x0.w, x1.x, x1.y, x1.z, x1.w};
            const float wlc[4] = {wl.x, wl.y, wl.z, wl.w};
            const float wrc[4] = {wr.x, wr.y, wr.z, wr.w};
#pragma unroll
            for (int r = 0; r < 8; ++r)
#pragma unroll
                for (int c = 0; c < 4; ++c)
                    acc[r][c] += ar[r] * wlc[c] + xr[r] * wrc[c];
        }
        __syncthreads();
    }

    const float4 bias = *(const float4*)&b1[j0 + tx * 4];
    const float bc[4] = {bias.x, bias.y, bias.z, bias.w};
#pragma unroll
    for (int r = 0; r < 8; ++r) {
        float4 v;
        v.x = fmaxf(acc[r][0] + bc[0], 0.f);
        v.y = fmaxf(acc[r][1] + bc[1], 0.f);
        v.z = fmaxf(acc[r][2] + bc[2], 0.f);
        v.w = fmaxf(acc[r][3] + bc[3], 0.f);
        *(float4*)&h[(size_t)(n0 + ty * 8 + r) * kHID + j0 + tx * 4] = v;
    }
}

// ---------------------------------------------------------------------------
// Layer-2 scatter (small: 2.6M atomics, keep simple for now)
// ---------------------------------------------------------------------------
__global__ __launch_bounds__(256)
void scatter2_kernel(const float* __restrict__ h, const int* __restrict__ src,
                     const int* __restrict__ dst, float* __restrict__ agg,
                     float* __restrict__ cnt) {
    const int e = blockIdx.x;
    const int s = src[e];
    const int d = dst[e];
    atomicAdd(&agg[(size_t)d * kHID + threadIdx.x],
              h[(size_t)s * kHID + threadIdx.x]);
    if (threadIdx.x == 0) atomicAdd(&cnt[d], 1.0f);
}

// ---------------------------------------------------------------------------
// Layer 2: logits = (agg2/cnt) @ W2l + b2 + h[:N0] @ W2r ; row log_softmax.
// One wave per output node.
// ---------------------------------------------------------------------------
__global__ __launch_bounds__(64)
void layer2_kernel(const float* __restrict__ agg2, const float* __restrict__ cnt2,
                   const float* __restrict__ h, const float* __restrict__ W2l,
                   const float* __restrict__ W2r, const float* __restrict__ b2,
                   float* __restrict__ out) {
    __shared__ float sa[kHID];
    __shared__ float sh[kHID];
    const int n = blockIdx.x;
    const int t = threadIdx.x;
    const float inv = 1.0f / fmaxf(cnt2[n], 1.0f);
    for (int k = t; k < kHID; k += 64) {
        sa[k] = agg2[(size_t)n * kHID + k] * inv;
        sh[k] = h[(size_t)n * kHID + k];
    }
    __syncthreads();

    float logit = 0.0f;
    if (t < kOUT) {
        logit = b2[t];
        for (int k = 0; k < kHID; ++k)
            logit += sa[k] * W2l[k * kOUT + t] + sh[k] * W2r[k * kOUT + t];
    }
    float m = (t < kOUT) ? logit : -INFINITY;
#pragma unroll
    for (int off = 32; off >= 1; off >>= 1)
        m = fmaxf(m, __shfl_xor(m, off));
    float e = (t < kOUT) ? expf(logit - m) : 0.0f;
    float s = e;
#pragma unroll
    for (int off = 32; off >= 1; off >>= 1)
        s += __shfl_xor(s, off);
    if (t < kOUT)
        out[(size_t)n * kOUT + t] = logit - m - logf(s);
}

// ---------------------------------------------------------------------------
extern "C" void kernel_launch(void* const* d_in, const int* in_sizes, int n_in,
                              void* d_out, int out_size, void* d_ws, size_t ws_size,
                              hipStream_t stream) {
    const float* x    = (const float*)d_in[0];
    const int*   src1 = (const int*)d_in[1];
    const int*   dst1 = (const int*)d_in[2];
    const int*   src2 = (const int*)d_in[3];
    const int*   dst2 = (const int*)d_in[4];
    const float* W1l  = (const float*)d_in[5];
    const float* W1r  = (const float*)d_in[6];
    const float* b1   = (const float*)d_in[7];
    const float* W2l  = (const float*)d_in[8];
    const float* W2r  = (const float*)d_in[9];
    const float* b2   = (const float*)d_in[10];
    float* out = (float*)d_out;

    // workspace layout: int region then 16B-aligned float region
    int* cnt_i = (int*)d_ws;                 // kN1
    int* cur_i = cnt_i + kN1;                // kN1
    int* off   = cur_i + kN1;                // kN1 + 1
    int* ebuf  = off + kN1 + 1;              // kE1
    size_t int_words = (size_t)3 * kN1 + 1 + kE1;
    int_words = (int_words + 3) & ~(size_t)3;

    float* agg1 = (float*)d_ws + int_words;  // kN1*kIN
    float* h    = agg1 + (size_t)kN1 * kIN;  // kN1*kHID
    float* agg2 = h + (size_t)kN1 * kHID;    // kN0*kHID
    float* cnt2 = agg2 + (size_t)kN0 * kHID; // kN0

    hipMemsetAsync(cnt_i, 0, (size_t)2 * kN1 * sizeof(int), stream);
    hipMemsetAsync(agg2, 0, ((size_t)kN0 * kHID + kN0) * sizeof(float), stream);

    constexpr int EB1 = (kE1 + 255) / 256;
    hist1_kernel<<<EB1, 256, 0, stream>>>(dst1, cnt_i);
    scan1_kernel<<<1, 256, 0, stream>>>(cnt_i, off);
    bucket1_kernel<<<EB1, 256, 0, stream>>>(src1, dst1, off, cur_i, ebuf);
    aggregate1_kernel<<<kN1, 128, 0, stream>>>(x, off, ebuf, agg1);
    layer1_kernel<<<dim3(kN1 / BM, kHID / BN), 256, 0, stream>>>(
        agg1, x, W1l, W1r, b1, h);
    scatter2_kernel<<<kE2, kHID, 0, stream>>>(h, src2, dst2, agg2, cnt2);
    layer2_kernel<<<kN0, 64, 0, stream>>>(agg2, cnt2, h, W2l, W2r, b2, out);
}

// Round 3
// 229.960 us; speedup vs baseline: 2.9532x; 1.7784x over previous
//
#include <hip/hip_runtime.h>
#include <hip/hip_bf16.h>
#include <math.h>

// Problem constants (from reference)
constexpr int kN2 = 180224, kN1 = 11264, kN0 = 1024;
constexpr int kE1 = 168960, kE2 = 10240;
constexpr int kIN = 602, kHID = 256, kOUT = 41;
constexpr int kKP = 608;  // kIN padded to multiple of 32 (MFMA K)

typedef __attribute__((ext_vector_type(8))) short bf16x8;
typedef __attribute__((ext_vector_type(4))) float f32x4;

// ---------------------------------------------------------------------------
// CSR build for layer-1 edges: histogram -> exclusive scan -> bucket scatter.
// ---------------------------------------------------------------------------
__global__ __launch_bounds__(256)
void hist1_kernel(const int* __restrict__ dst, int* __restrict__ cnt) {
    const int e = blockIdx.x * 256 + threadIdx.x;
    if (e < kE1) atomicAdd(&cnt[dst[e]], 1);
}

__global__ __launch_bounds__(256)
void scan1_kernel(const int* __restrict__ cnt, int* __restrict__ off) {
    __shared__ int part[256];
    const int t = threadIdx.x;
    constexpr int CH = kN1 / 256;  // 44
    const int base = t * CH;
    int s = 0;
    for (int i = 0; i < CH; ++i) s += cnt[base + i];
    part[t] = s;
    __syncthreads();
    for (int ofs = 1; ofs < 256; ofs <<= 1) {
        int v = (t >= ofs) ? part[t - ofs] : 0;
        __syncthreads();
        if (t >= ofs) part[t] += v;
        __syncthreads();
    }
    int run = (t == 0) ? 0 : part[t - 1];
    for (int i = 0; i < CH; ++i) {
        off[base + i] = run;
        run += cnt[base + i];
    }
    if (t == 255) off[kN1] = run;  // == kE1
}

__global__ __launch_bounds__(256)
void bucket1_kernel(const int* __restrict__ src, const int* __restrict__ dst,
                    const int* __restrict__ off, int* __restrict__ cur,
                    int* __restrict__ ebuf) {
    const int e = blockIdx.x * 256 + threadIdx.x;
    if (e < kE1) {
        const int d = dst[e];
        const int p = atomicAdd(&cur[d], 1);
        ebuf[off[d] + p] = src[e];
    }
}

// ---------------------------------------------------------------------------
// Aggregation layer 1: block per dst node, fp32 accumulate, write MEAN as
// bf16 into the padded [kN1][608] GEMM operand buffer.
// ---------------------------------------------------------------------------
__global__ __launch_bounds__(128)
void aggregate1_kernel(const float* __restrict__ x, const int* __restrict__ off,
                       const int* __restrict__ ebuf,
                       __hip_bfloat16* __restrict__ aggb) {
    const int d = blockIdx.x;
    const int t = threadIdx.x;
    const int b = off[d], e = off[d + 1];
    float acc[5] = {0.f, 0.f, 0.f, 0.f, 0.f};
    int s_next = (b < e) ? ebuf[b] : 0;
    for (int i = b; i < e; ++i) {
        const int s_cur = s_next;
        if (i + 1 < e) s_next = ebuf[i + 1];
        const float* row = x + (size_t)s_cur * kIN;
#pragma unroll
        for (int r = 0; r < 4; ++r) acc[r] += row[t + r * 128];
        if (t < kIN - 512) acc[4] += row[t + 512];
    }
    const float inv = 1.0f / fmaxf((float)(e - b), 1.0f);
    __hip_bfloat16* ar = aggb + (size_t)d * kKP;
#pragma unroll
    for (int r = 0; r < 4; ++r) ar[t + r * 128] = __float2bfloat16(acc[r] * inv);
    if (t < kIN - 512) ar[t + 512] = __float2bfloat16(acc[4] * inv);
    if (t < kKP - kIN) ar[kIN + t] = __float2bfloat16(0.f);  // zero pad
}

// ---------------------------------------------------------------------------
// Convert x[:N1] fp32 [kN1][602] -> bf16 [kN1][608] (zero-padded K tail).
// ---------------------------------------------------------------------------
__global__ __launch_bounds__(256)
void conv_x1_kernel(const float* __restrict__ x, __hip_bfloat16* __restrict__ xb) {
    const int row = blockIdx.x;
    for (int k = threadIdx.x; k < kKP; k += 256) {
        float v = (k < kIN) ? x[(size_t)row * kIN + k] : 0.f;
        xb[(size_t)row * kKP + k] = __float2bfloat16(v);
    }
}

// Convert+transpose W [602][256] -> Wt bf16 [256][608] (zero-padded K tail).
__global__ __launch_bounds__(256)
void conv_w_kernel(const float* __restrict__ W, __hip_bfloat16* __restrict__ Wt) {
    const int j = blockIdx.x;
    for (int k = threadIdx.x; k < kKP; k += 256) {
        float v = (k < kIN) ? W[(size_t)k * kHID + j] : 0.f;
        Wt[(size_t)j * kKP + k] = __float2bfloat16(v);
    }
}

// ---------------------------------------------------------------------------
// Layer-1 GEMM via MFMA: h = relu(agg @ W1l + b1 + x @ W1r), all bf16 inputs,
// fp32 accumulate. Block tile 64x128, 4 waves (each 64x32), K-chunk 32.
// A row-major [64][40] (pad 8 shorts -> ds_read_b128 2-way = free);
// B stored transposed [128][40]. Fragment: lane holds 8 contiguous k.
// C/D layout (verified m89/m91): col=lane&15, row=(lane>>4)*4+q.
// ---------------------------------------------------------------------------
__global__ __launch_bounds__(256)
void layer1_mfma(const ushort* __restrict__ aggb, const ushort* __restrict__ xb,
                 const ushort* __restrict__ wlt, const ushort* __restrict__ wrt,
                 const float* __restrict__ b1, float* __restrict__ h) {
    __shared__ ushort sA[2][64][40];
    __shared__ ushort sB[2][128][40];
    const int t = threadIdx.x;
    const int lane = t & 63, wid = t >> 6;
    const int n0 = blockIdx.x * 64;
    const int j0 = blockIdx.y * 128;

    f32x4 acc[4][2];
#pragma unroll
    for (int m = 0; m < 4; ++m)
#pragma unroll
        for (int n = 0; n < 2; ++n) acc[m][n] = (f32x4){0.f, 0.f, 0.f, 0.f};

    for (int k0 = 0; k0 < kKP; k0 += 32) {
        // stage: 512 A lane-tasks (16B each) + 1024 B lane-tasks
        for (int i = t; i < 1536; i += 256) {
            if (i < 512) {
                const int which = i >> 8;        // 0=agg, 1=x
                const int r = (i & 255) >> 2;    // 0..63
                const int k8 = i & 3;            // 16B chunk
                const ushort* src = (which ? xb : aggb) +
                                    (size_t)(n0 + r) * kKP + k0 + k8 * 8;
                *(uint4*)&sA[which][r][k8 * 8] = *(const uint4*)src;
            } else {
                const int i2 = i - 512;
                const int which = i2 >> 9;       // 0=Wl, 1=Wr
                const int c = (i2 & 511) >> 2;   // 0..127
                const int k8 = i2 & 3;
                const ushort* src = (which ? wrt : wlt) +
                                    (size_t)(j0 + c) * kKP + k0 + k8 * 8;
                *(uint4*)&sB[which][c][k8 * 8] = *(const uint4*)src;
            }
        }
        __syncthreads();
        const int krow = (lane >> 4) * 8;
        const int rl = lane & 15;
        bf16x8 af[4][2], bfr[2][2];
#pragma unroll
        for (int m = 0; m < 4; ++m)
#pragma unroll
            for (int p = 0; p < 2; ++p)
                af[m][p] = *(const bf16x8*)&sA[p][m * 16 + rl][krow];
#pragma unroll
        for (int n = 0; n < 2; ++n)
#pragma unroll
            for (int p = 0; p < 2; ++p)
                bfr[n][p] = *(const bf16x8*)&sB[p][wid * 32 + n * 16 + rl][krow];
#pragma unroll
        for (int m = 0; m < 4; ++m)
#pragma unroll
            for (int n = 0; n < 2; ++n) {
                acc[m][n] = __builtin_amdgcn_mfma_f32_16x16x32_bf16(
                    af[m][0], bfr[n][0], acc[m][n], 0, 0, 0);
                acc[m][n] = __builtin_amdgcn_mfma_f32_16x16x32_bf16(
                    af[m][1], bfr[n][1], acc[m][n], 0, 0, 0);
            }
        __syncthreads();
    }

    const int col_l = lane & 15, rq = lane >> 4;
#pragma unroll
    for (int m = 0; m < 4; ++m)
#pragma unroll
        for (int n = 0; n < 2; ++n) {
            const int gc = j0 + wid * 32 + n * 16 + col_l;
            const float bias = b1[gc];
#pragma unroll
            for (int q = 0; q < 4; ++q) {
                const int gr = n0 + m * 16 + rq * 4 + q;
                h[(size_t)gr * kHID + gc] = fmaxf(acc[m][n][q] + bias, 0.f);
            }
        }
}

// ---------------------------------------------------------------------------
// Layer-2 scatter (2.6M fp32 atomics into L2-resident 1MB, fine for now)
// ---------------------------------------------------------------------------
__global__ __launch_bounds__(256)
void scatter2_kernel(const float* __restrict__ h, const int* __restrict__ src,
                     const int* __restrict__ dst, float* __restrict__ agg,
                     float* __restrict__ cnt) {
    const int e = blockIdx.x;
    const int s = src[e];
    const int d = dst[e];
    atomicAdd(&agg[(size_t)d * kHID + threadIdx.x],
              h[(size_t)s * kHID + threadIdx.x]);
    if (threadIdx.x == 0) atomicAdd(&cnt[d], 1.0f);
}

// ---------------------------------------------------------------------------
// Layer 2: logits = (agg2/cnt) @ W2l + b2 + h[:N0] @ W2r ; row log_softmax.
// ---------------------------------------------------------------------------
__global__ __launch_bounds__(64)
void layer2_kernel(const float* __restrict__ agg2, const float* __restrict__ cnt2,
                   const float* __restrict__ h, const float* __restrict__ W2l,
                   const float* __restrict__ W2r, const float* __restrict__ b2,
                   float* __restrict__ out) {
    __shared__ float sa[kHID];
    __shared__ float sh[kHID];
    const int n = blockIdx.x;
    const int t = threadIdx.x;
    const float inv = 1.0f / fmaxf(cnt2[n], 1.0f);
    for (int k = t; k < kHID; k += 64) {
        sa[k] = agg2[(size_t)n * kHID + k] * inv;
        sh[k] = h[(size_t)n * kHID + k];
    }
    __syncthreads();

    float logit = 0.0f;
    if (t < kOUT) {
        logit = b2[t];
        for (int k = 0; k < kHID; ++k)
            logit += sa[k] * W2l[k * kOUT + t] + sh[k] * W2r[k * kOUT + t];
    }
    float m = (t < kOUT) ? logit : -INFINITY;
#pragma unroll
    for (int off = 32; off >= 1; off >>= 1)
        m = fmaxf(m, __shfl_xor(m, off));
    float e = (t < kOUT) ? expf(logit - m) : 0.0f;
    float s = e;
#pragma unroll
    for (int off = 32; off >= 1; off >>= 1)
        s += __shfl_xor(s, off);
    if (t < kOUT)
        out[(size_t)n * kOUT + t] = logit - m - logf(s);
}

// ---------------------------------------------------------------------------
extern "C" void kernel_launch(void* const* d_in, const int* in_sizes, int n_in,
                              void* d_out, int out_size, void* d_ws, size_t ws_size,
                              hipStream_t stream) {
    const float* x    = (const float*)d_in[0];
    const int*   src1 = (const int*)d_in[1];
    const int*   dst1 = (const int*)d_in[2];
    const int*   src2 = (const int*)d_in[3];
    const int*   dst2 = (const int*)d_in[4];
    const float* W1l  = (const float*)d_in[5];
    const float* W1r  = (const float*)d_in[6];
    const float* b1   = (const float*)d_in[7];
    const float* W2l  = (const float*)d_in[8];
    const float* W2r  = (const float*)d_in[9];
    const float* b2   = (const float*)d_in[10];
    float* out = (float*)d_out;

    // ---- workspace layout (16B-aligned segments) ----
    int* cnt_i = (int*)d_ws;                 // kN1
    int* cur_i = cnt_i + kN1;                // kN1
    int* off   = cur_i + kN1;                // kN1 + 1
    int* ebuf  = off + kN1 + 1;              // kE1
    size_t int_words = (size_t)3 * kN1 + 1 + kE1;
    int_words = (int_words + 7) & ~(size_t)7;  // 32B align

    __hip_bfloat16* aggb = (__hip_bfloat16*)((int*)d_ws + int_words);
    __hip_bfloat16* xb   = aggb + (size_t)kN1 * kKP;
    __hip_bfloat16* wlt  = xb + (size_t)kN1 * kKP;
    __hip_bfloat16* wrt  = wlt + (size_t)kHID * kKP;
    float* h    = (float*)(wrt + (size_t)kHID * kKP);
    float* agg2 = h + (size_t)kN1 * kHID;
    float* cnt2 = agg2 + (size_t)kN0 * kHID;

    hipMemsetAsync(cnt_i, 0, (size_t)2 * kN1 * sizeof(int), stream);
    hipMemsetAsync(agg2, 0, ((size_t)kN0 * kHID + kN0) * sizeof(float), stream);

    constexpr int EB1 = (kE1 + 255) / 256;
    hist1_kernel<<<EB1, 256, 0, stream>>>(dst1, cnt_i);
    scan1_kernel<<<1, 256, 0, stream>>>(cnt_i, off);
    bucket1_kernel<<<EB1, 256, 0, stream>>>(src1, dst1, off, cur_i, ebuf);

    conv_x1_kernel<<<kN1, 256, 0, stream>>>(x, xb);
    conv_w_kernel<<<kHID, 256, 0, stream>>>(W1l, wlt);
    conv_w_kernel<<<kHID, 256, 0, stream>>>(W1r, wrt);

    aggregate1_kernel<<<kN1, 128, 0, stream>>>(x, off, ebuf, aggb);

    layer1_mfma<<<dim3(kN1 / 64, kHID / 128), 256, 0, stream>>>(
        (const ushort*)aggb, (const ushort*)xb, (const ushort*)wlt,
        (const ushort*)wrt, b1, h);

    scatter2_kernel<<<kE2, kHID, 0, stream>>>(h, src2, dst2, agg2, cnt2);
    layer2_kernel<<<kN0, 64, 0, stream>>>(agg2, cnt2, h, W2l, W2r, b2, out);
}